// Round 9
// baseline (3006.748 us; speedup 1.0000x reference)
//
#include <hip/hip_runtime.h>
#include <hip/hip_bf16.h>
#include <math.h>

#define BB 8
#define DD 512
#define HH 8
#define EE 64
#define DI 1024
#define SS 64
#define RR 32
#define KCONV 4
#define DFF 2048
#define LL 1152
#define ML (BB*LL)        // 9216
#define XS (RR + 2*SS)    // 160
#define ZSTR 2048
#define YSTR 1536         // concat [y | attn] row stride

typedef short bf16x8 __attribute__((ext_vector_type(8)));
typedef float f32x4 __attribute__((ext_vector_type(4)));

#define GLD_LDS(g, l) \
  __builtin_amdgcn_global_load_lds((const __attribute__((address_space(1))) void*)(g), \
                                   (__attribute__((address_space(3))) void*)(l), 16, 0, 0)

__device__ __forceinline__ float bf2f(unsigned short u) {
  return __uint_as_float(((unsigned)u) << 16);
}

template<int IMM>
__device__ __forceinline__ float swz(float x) {
  return __uint_as_float((unsigned)__builtin_amdgcn_ds_swizzle((int)__float_as_uint(x), IMM));
}

// ---------------------------------------------------------------------------
// f32 -> bf16 conversion (contiguous)
// ---------------------------------------------------------------------------
__global__ __launch_bounds__(256) void cvt_bf16(
    const float* __restrict__ s, __hip_bfloat16* __restrict__ d, int n)
{
  const int i = (blockIdx.x * 256 + threadIdx.x) * 4;
  if (i + 3 < n) {
    const float4 v = *(const float4*)(s + i);
    __hip_bfloat16 t[4] = {__float2bfloat16(v.x), __float2bfloat16(v.y),
                           __float2bfloat16(v.z), __float2bfloat16(v.w)};
    *(ushort4*)(d + i) = *(const ushort4*)t;
  } else {
    for (int k = i; k < n; ++k) d[k] = __float2bfloat16(s[k]);
  }
}

// f32 -> bf16 with row repack: d[r*dststride + dstoff + c] = s[r*srclen + c]
__global__ __launch_bounds__(256) void cvt_pack(
    const float* __restrict__ s, __hip_bfloat16* __restrict__ d,
    int srclen, int dststride, int dstoff, int total)
{
  const int i = blockIdx.x * 256 + threadIdx.x;
  if (i >= total) return;
  const int r = i / srclen, c = i - r * srclen;
  d[(size_t)r * dststride + dstoff + c] = __float2bfloat16(s[i]);
}

// ---------------------------------------------------------------------------
// MFMA GEMM: C[m,n] = act( sum_k A[m,k]*W[n,k] + bias[n] ) + res[m,n]
// mode: 0 = f32 out; 1 = bf16 out; 3 = qkv split: n<1024 -> Cv[m*1024+n]
//       (bf16), n>=1024 -> V^T-per-head scatter into Cv2 [B*H, 64e, L].
// ---------------------------------------------------------------------------
__global__ __launch_bounds__(256) void gemm_mfma(
    const __hip_bfloat16* __restrict__ A, int lda,
    const __hip_bfloat16* __restrict__ W,
    const float* __restrict__ bias,
    const float* __restrict__ res,
    void* __restrict__ Cv, void* __restrict__ Cv2,
    int M, int N, int K, int act, int mode)
{
  __shared__ __align__(16) __hip_bfloat16 As[128 * 32];
  __shared__ __align__(16) __hip_bfloat16 Ws[128 * 32];
  const int tid = threadIdx.x;
  const int wid = tid >> 6, lane = tid & 63;
  const int wr = wid >> 1, wc = wid & 1;
  const int m0 = blockIdx.y << 7, n0 = blockIdx.x << 7;
  const int r1 = tid >> 2;
  const int c1 = (tid & 3) << 3;

  const __hip_bfloat16* ga0 = A + (size_t)(m0 + r1) * lda + c1;
  const __hip_bfloat16* ga1 = A + (size_t)(m0 + 64 + r1) * lda + c1;
  const __hip_bfloat16* gw0 = W + (size_t)(n0 + r1) * K + c1;
  const __hip_bfloat16* gw1 = W + (size_t)(n0 + 64 + r1) * K + c1;
  char* lA0 = (char*)As + wid * 1024;
  char* lA1 = lA0 + 4096;
  char* lW0 = (char*)Ws + wid * 1024;
  char* lW1 = lW0 + 4096;

  f32x4 acc[4][4];
#pragma unroll
  for (int i = 0; i < 4; ++i)
#pragma unroll
    for (int j = 0; j < 4; ++j) acc[i][j] = (f32x4){0.f, 0.f, 0.f, 0.f};

  const int fm = lane & 15;
  const int q8 = (lane >> 4) << 3;

  for (int kt = 0; kt < K; kt += 32) {
    __syncthreads();
    GLD_LDS(ga0, lA0); GLD_LDS(ga1, lA1);
    GLD_LDS(gw0, lW0); GLD_LDS(gw1, lW1);
    ga0 += 32; ga1 += 32; gw0 += 32; gw1 += 32;
    __syncthreads();

    bf16x8 af[4], wf[4];
#pragma unroll
    for (int i = 0; i < 4; ++i)
      af[i] = *(const bf16x8*)((const short*)As + (wr * 64 + i * 16 + fm) * 32 + q8);
#pragma unroll
    for (int j = 0; j < 4; ++j)
      wf[j] = *(const bf16x8*)((const short*)Ws + (wc * 64 + j * 16 + fm) * 32 + q8);
#pragma unroll
    for (int i = 0; i < 4; ++i)
#pragma unroll
      for (int j = 0; j < 4; ++j)
        acc[i][j] = __builtin_amdgcn_mfma_f32_16x16x32_bf16(af[i], wf[j], acc[i][j], 0, 0, 0);
  }

  const int rquad = (lane >> 4) << 2;
#pragma unroll
  for (int j = 0; j < 4; ++j) {
    const int n = n0 + wc * 64 + j * 16 + fm;
    if (n < N) {
      const float bv = bias ? bias[n] : 0.f;
#pragma unroll
      for (int i = 0; i < 4; ++i) {
        const int mb = m0 + wr * 64 + i * 16 + rquad;
#pragma unroll
        for (int r = 0; r < 4; ++r) {
          const int m = mb + r;
          float v = acc[i][j][r] + bv;
          if (act == 1) v = 0.5f * v * (1.f + erff(v * 0.70710678118654752f));
          else if (act == 2) v = fmaxf(v, 0.f) + log1pf(expf(-fabsf(v)));
          if (mode == 3) {
            if (n < 1024) {
              ((__hip_bfloat16*)Cv)[(size_t)m * 1024 + n] = __float2bfloat16(v);
            } else {
              const int e = n - 1024;
              const int bb2 = m / LL;
              const int key = m - bb2 * LL;
              ((__hip_bfloat16*)Cv2)[((size_t)(bb2 * HH + (e >> 6)) * EE + (e & 63)) * LL + key] =
                  __float2bfloat16(v);
            }
          } else {
            const size_t off = (size_t)m * N + n;
            if (res) v += res[off];
            if (mode == 1) ((__hip_bfloat16*)Cv)[off] = __float2bfloat16(v);
            else ((float*)Cv)[off] = v;
          }
        }
      }
    }
  }
}

// ---------------------------------------------------------------------------
// Causal depthwise conv1d (kernel 4) + SiLU.
// ---------------------------------------------------------------------------
__global__ __launch_bounds__(256) void conv_silu(
    const __hip_bfloat16* __restrict__ xz, const float* __restrict__ cw,
    const float* __restrict__ cb, __hip_bfloat16* __restrict__ uout)
{
  const size_t idx = (size_t)blockIdx.x * 256 + threadIdx.x;
  if (idx >= (size_t)ML * DI) return;
  const int di = (int)(idx & (DI - 1));
  const int row = (int)(idx >> 10);
  const int t = row % LL;
  float acc = cb[di];
#pragma unroll
  for (int k = 0; k < KCONV; ++k) {
    if (t - (KCONV - 1) + k >= 0)
      acc = fmaf((float)xz[(size_t)(row - (KCONV - 1 - k)) * ZSTR + di],
                 cw[di * KCONV + k], acc);
  }
  uout[idx] = __float2bfloat16(acc / (1.f + __expf(-acc)));
}

// ---------------------------------------------------------------------------
// Selective-scan v6: ONE CHANNEL PER WAVE, lane = state (64 states).
// 8192 waves = 8 waves/SIMD (full occupancy; VGPR<=64 via launch_bounds).
//  - step loop: no cross-lane ops; Pp[step&15] holds this lane's partial dot
//  - per-16-step frame: butterfly reduce-scatter xor 1/2/4/8 over Pp[16],
//    then xor16 (swizzle) + xor32 (shfl) on the single total
//  - B/C loads are lane-contiguous (128B/wave); dt/u wave-uniform
//  - exp2f with log2(e) folded into Aval; dt*u precomputed at load
// ---------------------------------------------------------------------------
#define SLOAD(P_, t0_) { _Pragma("unroll") for (int j = 0; j < 4; ++j) { \
    const float dtv = bf2f(dp[(size_t)((t0_)+j)*DI]); \
    P_##_dt[j] = dtv; \
    P_##_du[j] = dtv * bf2f(ubp[(size_t)((t0_)+j)*DI]); \
    P_##_B[j]  = Bp[(size_t)((t0_)+j)*XS]; \
    P_##_C[j]  = Cp[(size_t)((t0_)+j)*XS]; } }

#define SSTEP(P_, j, idx) { \
    const float dA = exp2f(P_##_dt[j] * Av); \
    h = fmaf(h, dA, P_##_du[j] * bf2f(P_##_B[j])); \
    Pp[(idx)] = h * bf2f(P_##_C[j]); }

#define SCOMP(P_, base_) { \
    SSTEP(P_, 0, (base_)+0) SSTEP(P_, 1, (base_)+1) \
    SSTEP(P_, 2, (base_)+2) SSTEP(P_, 3, (base_)+3) }

__global__ __launch_bounds__(256, 8) void scan_kernel(
    const __hip_bfloat16* __restrict__ delta, const __hip_bfloat16* __restrict__ ubf,
    const __hip_bfloat16* __restrict__ xz, const __hip_bfloat16* __restrict__ xdbc,
    const float* __restrict__ A_log, const float* __restrict__ D_ssm,
    __hip_bfloat16* __restrict__ yattn)
{
  const int wv = (int)((blockIdx.x * 256 + threadIdx.x) >> 6);   // 0..8191 = channel
  const int lane = threadIdx.x & 63;                             // = state
  const int b = wv >> 10;
  const int di = wv & (DI - 1);
  const float Av = -__expf(A_log[di * SS + lane]) * 1.4426950408889634f;
  const float Dd = D_ssm[di];
  const size_t rb = (size_t)b * LL;
  const unsigned short* __restrict__ dp  = (const unsigned short*)delta + rb * DI + di;
  const unsigned short* __restrict__ ubp = (const unsigned short*)ubf + rb * DI + di;
  const unsigned short* __restrict__ zbp = (const unsigned short*)xz + rb * ZSTR + DI + di;
  const unsigned short* __restrict__ Bp  = (const unsigned short*)xdbc + rb * XS + RR + lane;
  const unsigned short* __restrict__ Cp  = Bp + SS;
  __hip_bfloat16* __restrict__ yp = yattn + rb * YSTR + di;

  const int l15 = lane & 15;
  float h = 0.f;
  float Pp[16];
  float a_dt[4], a_du[4]; unsigned short a_B[4], a_C[4];
  float b_dt[4], b_du[4]; unsigned short b_B[4], b_C[4];

  float u_e = bf2f(ubp[(size_t)l15 * DI]);
  float z_e = bf2f(zbp[(size_t)l15 * ZSTR]);

  SLOAD(a, 0)
  for (int t0 = 0; t0 < LL; t0 += 16) {
    SLOAD(b, t0 + 4)
    SCOMP(a, 0)
    SLOAD(a, t0 + 8)
    SCOMP(b, 4)
    float u_n = 0.f, z_n = 0.f;
    if (t0 + 16 < LL) {
      u_n = bf2f(ubp[(size_t)(t0 + 16 + l15) * DI]);
      z_n = bf2f(zbp[(size_t)(t0 + 16 + l15) * ZSTR]);
    }
    SLOAD(b, t0 + 12)
    SCOMP(a, 8)
    if (t0 + 16 < LL) SLOAD(a, t0 + 16)
    SCOMP(b, 12)

    // butterfly reduce-scatter: 16 steps x 64 states -> lane (t&15) gets total
#pragma unroll
    for (int k2 = 0; k2 < 8; ++k2) {
      const float mn = (lane & 1) ? Pp[2*k2+1] : Pp[2*k2];
      const float ot = (lane & 1) ? Pp[2*k2]   : Pp[2*k2+1];
      Pp[k2] = mn + swz<0x041F>(ot);
    }
#pragma unroll
    for (int k2 = 0; k2 < 4; ++k2) {
      const float mn = (lane & 2) ? Pp[2*k2+1] : Pp[2*k2];
      const float ot = (lane & 2) ? Pp[2*k2]   : Pp[2*k2+1];
      Pp[k2] = mn + swz<0x081F>(ot);
    }
#pragma unroll
    for (int k2 = 0; k2 < 2; ++k2) {
      const float mn = (lane & 4) ? Pp[2*k2+1] : Pp[2*k2];
      const float ot = (lane & 4) ? Pp[2*k2]   : Pp[2*k2+1];
      Pp[k2] = mn + swz<0x101F>(ot);
    }
    {
      const float mn = (lane & 8) ? Pp[1] : Pp[0];
      const float ot = (lane & 8) ? Pp[0] : Pp[1];
      Pp[0] = mn + swz<0x201F>(ot);
    }
    Pp[0] += swz<0x401F>(Pp[0]);          // xor 16
    Pp[0] += __shfl_xor(Pp[0], 32, 64);   // xor 32

    const float yv = (Pp[0] + u_e * Dd) * (z_e / (1.f + __expf(-z_e)));
    if (lane < 16)
      yp[(size_t)(t0 + lane) * YSTR] = __float2bfloat16(yv);
    u_e = u_n; z_e = z_n;
  }
}

// ---------------------------------------------------------------------------
// MFMA flash attention (standalone). Writes yattn cols 1024..1535.
// ---------------------------------------------------------------------------
__global__ __launch_bounds__(256) void attn_mfma(
    const __hip_bfloat16* __restrict__ qk,
    const __hip_bfloat16* __restrict__ vtg, __hip_bfloat16* __restrict__ yattn)
{
  __shared__ __align__(16) __hip_bfloat16 Qs[64][72];
  __shared__ __align__(16) __hip_bfloat16 Ks[64][72];
  __shared__ __align__(16) __hip_bfloat16 Vts[64][72];
  __shared__ __align__(16) __hip_bfloat16 Ps[4][16][72];
  const int tid = threadIdx.x;
  const int w = tid >> 6, lane = tid & 63;
  const int bh = blockIdx.y;
  const int b = bh >> 3, hh = bh & 7;
  const int q0 = blockIdx.x << 6;
  const size_t qbase = (size_t)b * LL * 1024 + (size_t)hh * EE;
  const size_t vtbase = (size_t)bh * EE * LL;

  const int srow = tid >> 2, sch = (tid & 3) << 4;
  {
    const __hip_bfloat16* src = qk + qbase + (size_t)(q0 + srow) * 1024 + sch;
    *(uint4*)&Qs[srow][sch]     = *(const uint4*)src;
    *(uint4*)&Qs[srow][sch + 8] = *(const uint4*)(src + 8);
  }
  __syncthreads();

  const int fm = lane & 15;
  const int q8 = (lane >> 4) << 3;
  bf16x8 af0 = *(const bf16x8*)&Qs[w * 16 + fm][q8];
  bf16x8 af1 = *(const bf16x8*)&Qs[w * 16 + fm][32 + q8];

  f32x4 oacc[4];
  float m_i[4], l_i[4];
#pragma unroll
  for (int r = 0; r < 4; ++r) { m_i[r] = -INFINITY; l_i[r] = 0.f; }
#pragma unroll
  for (int j = 0; j < 4; ++j) oacc[j] = (f32x4){0.f, 0.f, 0.f, 0.f};

  for (int kt = 0; kt < LL / 64; ++kt) {
    const int k0 = kt << 6;
    __syncthreads();
    {
      const __hip_bfloat16* ksrc = qk + qbase + 512 + (size_t)(k0 + srow) * 1024 + sch;
      const __hip_bfloat16* vsrc = vtg + vtbase + (size_t)srow * LL + k0 + sch;
      *(uint4*)&Ks[srow][sch]      = *(const uint4*)ksrc;
      *(uint4*)&Ks[srow][sch + 8]  = *(const uint4*)(ksrc + 8);
      *(uint4*)&Vts[srow][sch]     = *(const uint4*)vsrc;
      *(uint4*)&Vts[srow][sch + 8] = *(const uint4*)(vsrc + 8);
    }
    __syncthreads();

    f32x4 sacc[4];
#pragma unroll
    for (int j = 0; j < 4; ++j) sacc[j] = (f32x4){0.f, 0.f, 0.f, 0.f};
#pragma unroll
    for (int j = 0; j < 4; ++j) {
      bf16x8 kf0 = *(const bf16x8*)&Ks[j * 16 + fm][q8];
      bf16x8 kf1 = *(const bf16x8*)&Ks[j * 16 + fm][32 + q8];
      sacc[j] = __builtin_amdgcn_mfma_f32_16x16x32_bf16(af0, kf0, sacc[j], 0, 0, 0);
      sacc[j] = __builtin_amdgcn_mfma_f32_16x16x32_bf16(af1, kf1, sacc[j], 0, 0, 0);
    }

    float alpha[4];
#pragma unroll
    for (int r = 0; r < 4; ++r) {
#pragma unroll
      for (int j = 0; j < 4; ++j) sacc[j][r] *= 0.125f;
      float mt = fmaxf(fmaxf(sacc[0][r], sacc[1][r]), fmaxf(sacc[2][r], sacc[3][r]));
      mt = fmaxf(mt, swz<0x041F>(mt)); mt = fmaxf(mt, swz<0x081F>(mt));
      mt = fmaxf(mt, swz<0x101F>(mt)); mt = fmaxf(mt, swz<0x201F>(mt));
      const float mn = fmaxf(m_i[r], mt);
      alpha[r] = __expf(m_i[r] - mn);
      m_i[r] = mn;
      float p[4], rs = 0.f;
#pragma unroll
      for (int j = 0; j < 4; ++j) { p[j] = __expf(sacc[j][r] - mn); rs += p[j]; }
      rs += swz<0x041F>(rs); rs += swz<0x081F>(rs);
      rs += swz<0x101F>(rs); rs += swz<0x201F>(rs);
      l_i[r] = l_i[r] * alpha[r] + rs;
      const int qrow = ((lane >> 4) << 2) + r;
#pragma unroll
      for (int j = 0; j < 4; ++j)
        Ps[w][qrow][j * 16 + fm] = __float2bfloat16(p[j]);
    }
#pragma unroll
    for (int j = 0; j < 4; ++j)
#pragma unroll
      for (int r = 0; r < 4; ++r) oacc[j][r] *= alpha[r];

    bf16x8 pf0 = *(const bf16x8*)&Ps[w][fm][q8];
    bf16x8 pf1 = *(const bf16x8*)&Ps[w][fm][32 + q8];
#pragma unroll
    for (int j = 0; j < 4; ++j) {
      bf16x8 v0 = *(const bf16x8*)&Vts[j * 16 + fm][q8];
      bf16x8 v1 = *(const bf16x8*)&Vts[j * 16 + fm][32 + q8];
      oacc[j] = __builtin_amdgcn_mfma_f32_16x16x32_bf16(pf0, v0, oacc[j], 0, 0, 0);
      oacc[j] = __builtin_amdgcn_mfma_f32_16x16x32_bf16(pf1, v1, oacc[j], 0, 0, 0);
    }
  }

#pragma unroll
  for (int r = 0; r < 4; ++r) {
    const float inv = 1.f / l_i[r];
    const int qq = q0 + w * 16 + ((lane >> 4) << 2) + r;
#pragma unroll
    for (int j = 0; j < 4; ++j)
      yattn[((size_t)b * LL + qq) * YSTR + 1024 + hh * EE + j * 16 + fm] =
          __float2bfloat16(oacc[j][r] * inv);
  }
}

// ---------------------------------------------------------------------------
// h = LN1(xf + combo); hn(bf16) = LN2(h).
// ---------------------------------------------------------------------------
__device__ __forceinline__ float block_sum512(float val, float* sm)
{
#pragma unroll
  for (int off = 32; off; off >>= 1) val += __shfl_xor(val, off, 64);
  const int wid = threadIdx.x >> 6;
  __syncthreads();
  if ((threadIdx.x & 63) == 0) sm[wid] = val;
  __syncthreads();
  return sm[0] + sm[1] + sm[2] + sm[3];
}

__global__ __launch_bounds__(256) void ln_fused(
    const float* __restrict__ xf, const float* __restrict__ combo,
    const float* __restrict__ g1, const float* __restrict__ b1,
    const float* __restrict__ g2, const float* __restrict__ b2,
    float* __restrict__ hout, __hip_bfloat16* __restrict__ hnout)
{
  __shared__ float sm[4];
  const size_t base = (size_t)blockIdx.x * DD;
  const int t = threadIdx.x;
  const float v0 = xf[base + t] + combo[base + t];
  const float v1 = xf[base + 256 + t] + combo[base + 256 + t];
  const float mean = block_sum512(v0 + v1, sm) * (1.f / DD);
  const float d0 = v0 - mean, d1 = v1 - mean;
  const float var = block_sum512(d0 * d0 + d1 * d1, sm) * (1.f / DD);
  const float rstd = rsqrtf(var + 1e-5f);
  const float h0 = d0 * rstd * g1[t] + b1[t];
  const float h1 = d1 * rstd * g1[t + 256] + b1[t + 256];
  hout[base + t] = h0;
  hout[base + 256 + t] = h1;
  const float mean2 = block_sum512(h0 + h1, sm) * (1.f / DD);
  const float e0 = h0 - mean2, e1 = h1 - mean2;
  const float var2 = block_sum512(e0 * e0 + e1 * e1, sm) * (1.f / DD);
  const float rstd2 = rsqrtf(var2 + 1e-6f);
  hnout[base + t] = __float2bfloat16(e0 * rstd2 * g2[t] + b2[t]);
  hnout[base + 256 + t] = __float2bfloat16(e1 * rstd2 * g2[t + 256] + b2[t + 256]);
}

// ---------------------------------------------------------------------------
extern "C" void kernel_launch(void* const* d_in, const int* in_sizes, int n_in,
                              void* d_out, int out_size, void* d_ws, size_t ws_size,
                              hipStream_t stream)
{
  const float* x         = (const float*)d_in[0];
  const float* Wq        = (const float*)d_in[2];
  const float* bq        = (const float*)d_in[3];
  const float* Wk        = (const float*)d_in[4];
  const float* bk        = (const float*)d_in[5];
  const float* Wv        = (const float*)d_in[6];
  const float* bv        = (const float*)d_in[7];
  const float* Wo        = (const float*)d_in[8];
  const float* bo        = (const float*)d_in[9];
  const float* in_proj_w = (const float*)d_in[10];
  const float* conv_w    = (const float*)d_in[11];
  const float* conv_b    = (const float*)d_in[12];
  const float* x_proj_w  = (const float*)d_in[13];
  const float* dt_proj_w = (const float*)d_in[14];
  const float* dt_proj_b = (const float*)d_in[15];
  const float* A_log     = (const float*)d_in[16];
  const float* D_ssm     = (const float*)d_in[17];
  const float* out_proj_w= (const float*)d_in[18];
  const float* ln1_g     = (const float*)d_in[19];
  const float* ln1_b     = (const float*)d_in[20];
  const float* ffn_w1    = (const float*)d_in[21];
  const float* ffn_b1    = (const float*)d_in[22];
  const float* ffn_w2    = (const float*)d_in[23];
  const float* ffn_b2    = (const float*)d_in[24];
  const float* ln2_g     = (const float*)d_in[25];
  const float* ln2_b     = (const float*)d_in[26];
  float* out = (float*)d_out;

  // ---- workspace layout (f32-unit offsets), peak 154.5 MB
  float* ws = (float*)d_ws;
  const size_t OF_XBF = 2506752;               // xbf bf16 | later hnbf
  const size_t OF_XZ  = OF_XBF + 2359296;      // xz bf16 [ML,2048]
  const size_t OF_UBF = OF_XZ + 9437184;       // ubf bf16 | later combo f32
  const size_t OF_XD  = OF_UBF + 4718592;      // xdbc bf16
  const size_t OF_DF  = OF_XD + 737280;        // deltab bf16 | ffbf (part 1)
  const size_t OF_QKV = OF_DF + 4718592;       // qkbuf+vtbf bf16 | ffbf (part 2)
  const size_t OF_YA  = OF_QKV + 7077888;      // yattn bf16 [ML,1536] | later hbuf f32
  const size_t OF_QB  = OF_YA + 7077888;       // qkv bias f32 [1536]

  __hip_bfloat16* wbf     = (__hip_bfloat16*)ws;
  __hip_bfloat16* xbf     = (__hip_bfloat16*)(ws + OF_XBF);
  __hip_bfloat16* hnbf    = (__hip_bfloat16*)(ws + OF_XBF);
  __hip_bfloat16* xz      = (__hip_bfloat16*)(ws + OF_XZ);
  __hip_bfloat16* ubf     = (__hip_bfloat16*)(ws + OF_UBF);
  float*          combo   = ws + OF_UBF;
  __hip_bfloat16* xdbc_bf = (__hip_bfloat16*)(ws + OF_XD);
  __hip_bfloat16* deltab  = (__hip_bfloat16*)(ws + OF_DF);
  __hip_bfloat16* ffbf    = (__hip_bfloat16*)(ws + OF_DF);
  __hip_bfloat16* qkbuf   = (__hip_bfloat16*)(ws + OF_QKV);
  __hip_bfloat16* vtbf    = (__hip_bfloat16*)(ws + OF_QKV + 4718592);
  __hip_bfloat16* yattn   = (__hip_bfloat16*)(ws + OF_YA);
  float*          hbuf    = ws + OF_YA;
  float*          qkvbias = ws + OF_QB;

  // weight offsets (bf16 elements) in wbf
  const size_t w_inproj = 0;          // 1048576
  const size_t w_xproj  = 1048576;    // rows padded 160->256 (262144)
  const size_t w_dt     = 1310720;    // 32768
  const size_t w_cat    = 1343488;    // [512, 1536] = out_proj | Wo (786432)
  const size_t w_q      = 2129920;    // q,k,v contiguous 1536x512 (786432)
  const size_t w_f1     = 2916352;    // 1048576
  const size_t w_f2     = 3964928;    // 1048576; total 5013504 bf16

  const dim3 thr(256);
#define CVT(src, dst, n) cvt_bf16<<<dim3(((n)/4 + 255)/256), thr, 0, stream>>>(src, dst, n)
#define GEMM(Abf, lda_, Woff, Bptr, Rptr, Cptr, C2ptr, N_, K_, act_, md_) \
  gemm_mfma<<<dim3((N_ + 127)/128, ML/128), thr, 0, stream>>>( \
      Abf, lda_, wbf + (Woff), Bptr, Rptr, (void*)(Cptr), (void*)(C2ptr), ML, N_, K_, act_, md_)

  hipMemsetAsync((void*)(wbf + w_xproj + (size_t)160 * 1024), 0, (size_t)96 * 1024 * 2, stream);
  CVT(in_proj_w, wbf + w_inproj, 1048576);
  CVT(x_proj_w,  wbf + w_xproj,  163840);
  CVT(dt_proj_w, wbf + w_dt,     32768);
  cvt_pack<<<dim3((524288 + 255)/256), thr, 0, stream>>>(
      out_proj_w, wbf + w_cat, 1024, 1536, 0,    524288);
  cvt_pack<<<dim3((262144 + 255)/256), thr, 0, stream>>>(
      Wo,         wbf + w_cat, 512,  1536, 1024, 262144);
  CVT(Wq,        wbf + w_q,           262144);
  CVT(Wk,        wbf + w_q + 262144,  262144);
  CVT(Wv,        wbf + w_q + 524288,  262144);
  CVT(ffn_w1,    wbf + w_f1,    1048576);
  CVT(ffn_w2,    wbf + w_f2,    1048576);
  CVT(x,         xbf,           ML * DD);
  hipMemcpyAsync(qkvbias,        bq, 512 * sizeof(float), hipMemcpyDeviceToDevice, stream);
  hipMemcpyAsync(qkvbias + 512,  bk, 512 * sizeof(float), hipMemcpyDeviceToDevice, stream);
  hipMemcpyAsync(qkvbias + 1024, bv, 512 * sizeof(float), hipMemcpyDeviceToDevice, stream);

  // ---- mamba preprocessing
  GEMM(xbf, DD, w_inproj, nullptr, nullptr, xz, nullptr, 2 * DI, DD, 0, 1);
  conv_silu<<<dim3((ML * DI) / 256), thr, 0, stream>>>(xz, conv_w, conv_b, ubf);
  GEMM(ubf, DI, w_xproj, nullptr, nullptr, xdbc_bf, nullptr, XS, DI, 0, 1);
  GEMM(xdbc_bf, XS, w_dt, dt_proj_b, nullptr, deltab, nullptr, DI, RR, 2, 1);

  // ---- attention (QKV fused GEMM, then flash attention)
  GEMM(xbf, DD, w_q, qkvbias, nullptr, qkbuf, vtbf, 3 * DD, DD, 0, 3);
  attn_mfma<<<dim3(LL / 64, BB * HH), thr, 0, stream>>>(qkbuf, vtbf, yattn);

  // ---- selective scan (8192 waves, full occupancy)
  scan_kernel<<<dim3(2048), thr, 0, stream>>>(
      deltab, ubf, xz, xdbc_bf, A_log, D_ssm, yattn);

  // ---- combined output projection: combo = y@out_proj^T + attn@Wo^T + bo
  GEMM(yattn, YSTR, w_cat, bo, nullptr, combo, nullptr, DD, YSTR, 0, 0);

  // ---- combine + LN1 + LN2
  ln_fused<<<dim3(ML), thr, 0, stream>>>(x, combo, ln1_g, ln1_b,
                                         ln2_g, ln2_b, hbuf, hnbf);

  // ---- FFN
  GEMM(hnbf, DD, w_f1, ffn_b1, nullptr, ffbf, nullptr, DFF, DD, 1, 1);
  GEMM(ffbf, DFF, w_f2, ffn_b2, hbuf, out, nullptr, DD, DFF, 0, 0);
#undef GEMM
#undef CVT
}

// Round 10
// 2420.558 us; speedup vs baseline: 1.2422x; 1.2422x over previous
//
#include <hip/hip_runtime.h>
#include <hip/hip_bf16.h>
#include <math.h>

#define BB 8
#define DD 512
#define HH 8
#define EE 64
#define DI 1024
#define SS 64
#define RR 32
#define KCONV 4
#define DFF 2048
#define LL 1152
#define ML (BB*LL)        // 9216
#define XS (RR + 2*SS)    // 160
#define ZSTR 2048
#define YSTR 1536         // concat [y | attn] row stride

typedef short bf16x8 __attribute__((ext_vector_type(8)));
typedef float f32x4 __attribute__((ext_vector_type(4)));
typedef unsigned short u16x2 __attribute__((ext_vector_type(2)));

#define GLD_LDS(g, l) \
  __builtin_amdgcn_global_load_lds((const __attribute__((address_space(1))) void*)(g), \
                                   (__attribute__((address_space(3))) void*)(l), 16, 0, 0)

__device__ __forceinline__ float bf2f(unsigned short u) {
  return __uint_as_float(((unsigned)u) << 16);
}

template<int IMM>
__device__ __forceinline__ float swz(float x) {
  return __uint_as_float((unsigned)__builtin_amdgcn_ds_swizzle((int)__float_as_uint(x), IMM));
}

// ---------------------------------------------------------------------------
// f32 -> bf16 conversion (contiguous)
// ---------------------------------------------------------------------------
__global__ __launch_bounds__(256) void cvt_bf16(
    const float* __restrict__ s, __hip_bfloat16* __restrict__ d, int n)
{
  const int i = (blockIdx.x * 256 + threadIdx.x) * 4;
  if (i + 3 < n) {
    const float4 v = *(const float4*)(s + i);
    __hip_bfloat16 t[4] = {__float2bfloat16(v.x), __float2bfloat16(v.y),
                           __float2bfloat16(v.z), __float2bfloat16(v.w)};
    *(ushort4*)(d + i) = *(const ushort4*)t;
  } else {
    for (int k = i; k < n; ++k) d[k] = __float2bfloat16(s[k]);
  }
}

// f32 -> bf16 with row repack: d[r*dststride + dstoff + c] = s[r*srclen + c]
__global__ __launch_bounds__(256) void cvt_pack(
    const float* __restrict__ s, __hip_bfloat16* __restrict__ d,
    int srclen, int dststride, int dstoff, int total)
{
  const int i = blockIdx.x * 256 + threadIdx.x;
  if (i >= total) return;
  const int r = i / srclen, c = i - r * srclen;
  d[(size_t)r * dststride + dstoff + c] = __float2bfloat16(s[i]);
}

// ---------------------------------------------------------------------------
// MFMA GEMM: C[m,n] = act( sum_k A[m,k]*W[n,k] + bias[n] ) + res[m,n]
// mode: 0 = f32 out; 1 = bf16 out; 3 = qkv split: n<1024 -> Cv[m*1024+n]
//       (bf16), n>=1024 -> V^T-per-head scatter into Cv2 [B*H, 64e, L].
// ---------------------------------------------------------------------------
__global__ __launch_bounds__(256) void gemm_mfma(
    const __hip_bfloat16* __restrict__ A, int lda,
    const __hip_bfloat16* __restrict__ W,
    const float* __restrict__ bias,
    const float* __restrict__ res,
    void* __restrict__ Cv, void* __restrict__ Cv2,
    int M, int N, int K, int act, int mode)
{
  __shared__ __align__(16) __hip_bfloat16 As[128 * 32];
  __shared__ __align__(16) __hip_bfloat16 Ws[128 * 32];
  const int tid = threadIdx.x;
  const int wid = tid >> 6, lane = tid & 63;
  const int wr = wid >> 1, wc = wid & 1;
  const int m0 = blockIdx.y << 7, n0 = blockIdx.x << 7;
  const int r1 = tid >> 2;
  const int c1 = (tid & 3) << 3;

  const __hip_bfloat16* ga0 = A + (size_t)(m0 + r1) * lda + c1;
  const __hip_bfloat16* ga1 = A + (size_t)(m0 + 64 + r1) * lda + c1;
  const __hip_bfloat16* gw0 = W + (size_t)(n0 + r1) * K + c1;
  const __hip_bfloat16* gw1 = W + (size_t)(n0 + 64 + r1) * K + c1;
  char* lA0 = (char*)As + wid * 1024;
  char* lA1 = lA0 + 4096;
  char* lW0 = (char*)Ws + wid * 1024;
  char* lW1 = lW0 + 4096;

  f32x4 acc[4][4];
#pragma unroll
  for (int i = 0; i < 4; ++i)
#pragma unroll
    for (int j = 0; j < 4; ++j) acc[i][j] = (f32x4){0.f, 0.f, 0.f, 0.f};

  const int fm = lane & 15;
  const int q8 = (lane >> 4) << 3;

  for (int kt = 0; kt < K; kt += 32) {
    __syncthreads();
    GLD_LDS(ga0, lA0); GLD_LDS(ga1, lA1);
    GLD_LDS(gw0, lW0); GLD_LDS(gw1, lW1);
    ga0 += 32; ga1 += 32; gw0 += 32; gw1 += 32;
    __syncthreads();

    bf16x8 af[4], wf[4];
#pragma unroll
    for (int i = 0; i < 4; ++i)
      af[i] = *(const bf16x8*)((const short*)As + (wr * 64 + i * 16 + fm) * 32 + q8);
#pragma unroll
    for (int j = 0; j < 4; ++j)
      wf[j] = *(const bf16x8*)((const short*)Ws + (wc * 64 + j * 16 + fm) * 32 + q8);
#pragma unroll
    for (int i = 0; i < 4; ++i)
#pragma unroll
      for (int j = 0; j < 4; ++j)
        acc[i][j] = __builtin_amdgcn_mfma_f32_16x16x32_bf16(af[i], wf[j], acc[i][j], 0, 0, 0);
  }

  const int rquad = (lane >> 4) << 2;
#pragma unroll
  for (int j = 0; j < 4; ++j) {
    const int n = n0 + wc * 64 + j * 16 + fm;
    if (n < N) {
      const float bv = bias ? bias[n] : 0.f;
#pragma unroll
      for (int i = 0; i < 4; ++i) {
        const int mb = m0 + wr * 64 + i * 16 + rquad;
#pragma unroll
        for (int r = 0; r < 4; ++r) {
          const int m = mb + r;
          float v = acc[i][j][r] + bv;
          if (act == 1) v = 0.5f * v * (1.f + erff(v * 0.70710678118654752f));
          else if (act == 2) v = fmaxf(v, 0.f) + log1pf(expf(-fabsf(v)));
          if (mode == 3) {
            if (n < 1024) {
              ((__hip_bfloat16*)Cv)[(size_t)m * 1024 + n] = __float2bfloat16(v);
            } else {
              const int e = n - 1024;
              const int bb2 = m / LL;
              const int key = m - bb2 * LL;
              ((__hip_bfloat16*)Cv2)[((size_t)(bb2 * HH + (e >> 6)) * EE + (e & 63)) * LL + key] =
                  __float2bfloat16(v);
            }
          } else {
            const size_t off = (size_t)m * N + n;
            if (res) v += res[off];
            if (mode == 1) ((__hip_bfloat16*)Cv)[off] = __float2bfloat16(v);
            else ((float*)Cv)[off] = v;
          }
        }
      }
    }
  }
}

// ---------------------------------------------------------------------------
// Causal depthwise conv1d (kernel 4) + SiLU.
// ---------------------------------------------------------------------------
__global__ __launch_bounds__(256) void conv_silu(
    const __hip_bfloat16* __restrict__ xz, const float* __restrict__ cw,
    const float* __restrict__ cb, __hip_bfloat16* __restrict__ uout)
{
  const size_t idx = (size_t)blockIdx.x * 256 + threadIdx.x;
  if (idx >= (size_t)ML * DI) return;
  const int di = (int)(idx & (DI - 1));
  const int row = (int)(idx >> 10);
  const int t = row % LL;
  float acc = cb[di];
#pragma unroll
  for (int k = 0; k < KCONV; ++k) {
    if (t - (KCONV - 1) + k >= 0)
      acc = fmaf((float)xz[(size_t)(row - (KCONV - 1 - k)) * ZSTR + di],
                 cw[di * KCONV + k], acc);
  }
  uout[idx] = __float2bfloat16(acc / (1.f + __expf(-acc)));
}

// ---------------------------------------------------------------------------
// Selective-scan v5.5: 2 channels/wave, 32 lanes/channel, 2 states/lane.
// 4096 waves = 4 waves/SIMD (2x v5's TLP; B/C still one 128B line per wave,
// shared by both channels in-register -> traffic only 2x v5, ~240MB).
//  - step loop: no cross-lane ops; Pp[step&15] holds this lane's partial dot
//  - per-16-step frame: butterfly reduce-scatter xor 1/2/4/8 (16-lane groups)
//    + xor16 fold -> lanes (lane&31)<16 hold their channel's step totals
//  - 4-tile ring prefetch (12-step lookahead) + frame-ahead u/z prefetch
// ---------------------------------------------------------------------------
#define SLOAD(P_, t0_) { _Pragma("unroll") for (int j = 0; j < 4; ++j) { \
    const float dtv = bf2f(dp[(size_t)((t0_)+j)*DI]); \
    P_##_dt[j] = dtv; \
    P_##_du[j] = dtv * bf2f(ubp[(size_t)((t0_)+j)*DI]); \
    P_##_B[j]  = *(const u16x2*)(Bp + (size_t)((t0_)+j)*XS); \
    P_##_C[j]  = *(const u16x2*)(Cp + (size_t)((t0_)+j)*XS); } }

#define SSTEP(P_, j, idx) { \
    h0 = fmaf(h0, exp2f(P_##_dt[j] * Av0), P_##_du[j] * bf2f(P_##_B[j][0])); \
    h1 = fmaf(h1, exp2f(P_##_dt[j] * Av1), P_##_du[j] * bf2f(P_##_B[j][1])); \
    float part = h0 * bf2f(P_##_C[j][0]); \
    part = fmaf(h1, bf2f(P_##_C[j][1]), part); \
    Pp[(idx)] = part; }

#define SCOMP(P_, base_) { \
    SSTEP(P_, 0, (base_)+0) SSTEP(P_, 1, (base_)+1) \
    SSTEP(P_, 2, (base_)+2) SSTEP(P_, 3, (base_)+3) }

__global__ __launch_bounds__(256, 4) void scan_kernel(
    const __hip_bfloat16* __restrict__ delta, const __hip_bfloat16* __restrict__ ubf,
    const __hip_bfloat16* __restrict__ xz, const __hip_bfloat16* __restrict__ xdbc,
    const float* __restrict__ A_log, const float* __restrict__ D_ssm,
    __hip_bfloat16* __restrict__ yattn)
{
  const int wv = (int)((blockIdx.x * 256 + threadIdx.x) >> 6);   // 0..4095
  const int lane = threadIdx.x & 63;
  const int c = lane >> 5;             // channel within wave (0/1)
  const int s = lane & 31;             // state-pair index (states 2s, 2s+1)
  const int l15 = lane & 15;
  const int g = (wv << 1) + c;         // global channel
  const int b = g >> 10;
  const int di = g & (DI - 1);
  const float Av0 = -__expf(A_log[di * SS + 2 * s])     * 1.4426950408889634f;
  const float Av1 = -__expf(A_log[di * SS + 2 * s + 1]) * 1.4426950408889634f;
  const float Dd = D_ssm[di];
  const size_t rb = (size_t)b * LL;
  const unsigned short* __restrict__ dp  = (const unsigned short*)delta + rb * DI + di;
  const unsigned short* __restrict__ ubp = (const unsigned short*)ubf + rb * DI + di;
  const unsigned short* __restrict__ zbp = (const unsigned short*)xz + rb * ZSTR + DI + di;
  const unsigned short* __restrict__ Bp  = (const unsigned short*)xdbc + rb * XS + RR + 2 * s;
  const unsigned short* __restrict__ Cp  = Bp + SS;
  __hip_bfloat16* __restrict__ yp = yattn + rb * YSTR + di;

  float h0 = 0.f, h1 = 0.f;
  float Pp[16];
  float a_dt[4], a_du[4]; u16x2 a_B[4], a_C[4];
  float b_dt[4], b_du[4]; u16x2 b_B[4], b_C[4];
  float c_dt[4], c_du[4]; u16x2 c_B[4], c_C[4];
  float d_dt[4], d_du[4]; u16x2 d_B[4], d_C[4];

  float u_e = bf2f(ubp[(size_t)l15 * DI]);
  float z_e = bf2f(zbp[(size_t)l15 * ZSTR]);

  SLOAD(a, 0) SLOAD(b, 4) SLOAD(c, 8)
  for (int t0 = 0; t0 < LL; t0 += 16) {
    SLOAD(d, t0 + 12)
    SCOMP(a, 0)
    if (t0 + 16 < LL) SLOAD(a, t0 + 16)
    SCOMP(b, 4)
    float u_n = 0.f, z_n = 0.f;
    if (t0 + 16 < LL) {
      u_n = bf2f(ubp[(size_t)(t0 + 16 + l15) * DI]);
      z_n = bf2f(zbp[(size_t)(t0 + 16 + l15) * ZSTR]);
    }
    if (t0 + 20 < LL) SLOAD(b, t0 + 20)
    SCOMP(c, 8)
    if (t0 + 24 < LL) SLOAD(c, t0 + 24)
    SCOMP(d, 12)

    // butterfly reduce-scatter within 16-lane groups, then fold the two
    // halves of each channel's 32 lanes
#pragma unroll
    for (int k2 = 0; k2 < 8; ++k2) {
      const float mn = (lane & 1) ? Pp[2*k2+1] : Pp[2*k2];
      const float ot = (lane & 1) ? Pp[2*k2]   : Pp[2*k2+1];
      Pp[k2] = mn + swz<0x041F>(ot);
    }
#pragma unroll
    for (int k2 = 0; k2 < 4; ++k2) {
      const float mn = (lane & 2) ? Pp[2*k2+1] : Pp[2*k2];
      const float ot = (lane & 2) ? Pp[2*k2]   : Pp[2*k2+1];
      Pp[k2] = mn + swz<0x081F>(ot);
    }
#pragma unroll
    for (int k2 = 0; k2 < 2; ++k2) {
      const float mn = (lane & 4) ? Pp[2*k2+1] : Pp[2*k2];
      const float ot = (lane & 4) ? Pp[2*k2]   : Pp[2*k2+1];
      Pp[k2] = mn + swz<0x101F>(ot);
    }
    {
      const float mn = (lane & 8) ? Pp[1] : Pp[0];
      const float ot = (lane & 8) ? Pp[0] : Pp[1];
      Pp[0] = mn + swz<0x201F>(ot);
    }
    Pp[0] += swz<0x401F>(Pp[0]);   // fold lanes l and l^16 (same channel)

    const float yv = (Pp[0] + u_e * Dd) * (z_e / (1.f + __expf(-z_e)));
    if ((lane & 31) < 16)
      yp[(size_t)(t0 + l15) * YSTR] = __float2bfloat16(yv);
    u_e = u_n; z_e = z_n;
  }
}

// ---------------------------------------------------------------------------
// MFMA flash attention (standalone). Writes yattn cols 1024..1535.
// ---------------------------------------------------------------------------
__global__ __launch_bounds__(256) void attn_mfma(
    const __hip_bfloat16* __restrict__ qk,
    const __hip_bfloat16* __restrict__ vtg, __hip_bfloat16* __restrict__ yattn)
{
  __shared__ __align__(16) __hip_bfloat16 Qs[64][72];
  __shared__ __align__(16) __hip_bfloat16 Ks[64][72];
  __shared__ __align__(16) __hip_bfloat16 Vts[64][72];
  __shared__ __align__(16) __hip_bfloat16 Ps[4][16][72];
  const int tid = threadIdx.x;
  const int w = tid >> 6, lane = tid & 63;
  const int bh = blockIdx.y;
  const int b = bh >> 3, hh = bh & 7;
  const int q0 = blockIdx.x << 6;
  const size_t qbase = (size_t)b * LL * 1024 + (size_t)hh * EE;
  const size_t vtbase = (size_t)bh * EE * LL;

  const int srow = tid >> 2, sch = (tid & 3) << 4;
  {
    const __hip_bfloat16* src = qk + qbase + (size_t)(q0 + srow) * 1024 + sch;
    *(uint4*)&Qs[srow][sch]     = *(const uint4*)src;
    *(uint4*)&Qs[srow][sch + 8] = *(const uint4*)(src + 8);
  }
  __syncthreads();

  const int fm = lane & 15;
  const int q8 = (lane >> 4) << 3;
  bf16x8 af0 = *(const bf16x8*)&Qs[w * 16 + fm][q8];
  bf16x8 af1 = *(const bf16x8*)&Qs[w * 16 + fm][32 + q8];

  f32x4 oacc[4];
  float m_i[4], l_i[4];
#pragma unroll
  for (int r = 0; r < 4; ++r) { m_i[r] = -INFINITY; l_i[r] = 0.f; }
#pragma unroll
  for (int j = 0; j < 4; ++j) oacc[j] = (f32x4){0.f, 0.f, 0.f, 0.f};

  for (int kt = 0; kt < LL / 64; ++kt) {
    const int k0 = kt << 6;
    __syncthreads();
    {
      const __hip_bfloat16* ksrc = qk + qbase + 512 + (size_t)(k0 + srow) * 1024 + sch;
      const __hip_bfloat16* vsrc = vtg + vtbase + (size_t)srow * LL + k0 + sch;
      *(uint4*)&Ks[srow][sch]      = *(const uint4*)ksrc;
      *(uint4*)&Ks[srow][sch + 8]  = *(const uint4*)(ksrc + 8);
      *(uint4*)&Vts[srow][sch]     = *(const uint4*)vsrc;
      *(uint4*)&Vts[srow][sch + 8] = *(const uint4*)(vsrc + 8);
    }
    __syncthreads();

    f32x4 sacc[4];
#pragma unroll
    for (int j = 0; j < 4; ++j) sacc[j] = (f32x4){0.f, 0.f, 0.f, 0.f};
#pragma unroll
    for (int j = 0; j < 4; ++j) {
      bf16x8 kf0 = *(const bf16x8*)&Ks[j * 16 + fm][q8];
      bf16x8 kf1 = *(const bf16x8*)&Ks[j * 16 + fm][32 + q8];
      sacc[j] = __builtin_amdgcn_mfma_f32_16x16x32_bf16(af0, kf0, sacc[j], 0, 0, 0);
      sacc[j] = __builtin_amdgcn_mfma_f32_16x16x32_bf16(af1, kf1, sacc[j], 0, 0, 0);
    }

    float alpha[4];
#pragma unroll
    for (int r = 0; r < 4; ++r) {
#pragma unroll
      for (int j = 0; j < 4; ++j) sacc[j][r] *= 0.125f;
      float mt = fmaxf(fmaxf(sacc[0][r], sacc[1][r]), fmaxf(sacc[2][r], sacc[3][r]));
      mt = fmaxf(mt, swz<0x041F>(mt)); mt = fmaxf(mt, swz<0x081F>(mt));
      mt = fmaxf(mt, swz<0x101F>(mt)); mt = fmaxf(mt, swz<0x201F>(mt));
      const float mn = fmaxf(m_i[r], mt);
      alpha[r] = __expf(m_i[r] - mn);
      m_i[r] = mn;
      float p[4], rs = 0.f;
#pragma unroll
      for (int j = 0; j < 4; ++j) { p[j] = __expf(sacc[j][r] - mn); rs += p[j]; }
      rs += swz<0x041F>(rs); rs += swz<0x081F>(rs);
      rs += swz<0x101F>(rs); rs += swz<0x201F>(rs);
      l_i[r] = l_i[r] * alpha[r] + rs;
      const int qrow = ((lane >> 4) << 2) + r;
#pragma unroll
      for (int j = 0; j < 4; ++j)
        Ps[w][qrow][j * 16 + fm] = __float2bfloat16(p[j]);
    }
#pragma unroll
    for (int j = 0; j < 4; ++j)
#pragma unroll
      for (int r = 0; r < 4; ++r) oacc[j][r] *= alpha[r];

    bf16x8 pf0 = *(const bf16x8*)&Ps[w][fm][q8];
    bf16x8 pf1 = *(const bf16x8*)&Ps[w][fm][32 + q8];
#pragma unroll
    for (int j = 0; j < 4; ++j) {
      bf16x8 v0 = *(const bf16x8*)&Vts[j * 16 + fm][q8];
      bf16x8 v1 = *(const bf16x8*)&Vts[j * 16 + fm][32 + q8];
      oacc[j] = __builtin_amdgcn_mfma_f32_16x16x32_bf16(pf0, v0, oacc[j], 0, 0, 0);
      oacc[j] = __builtin_amdgcn_mfma_f32_16x16x32_bf16(pf1, v1, oacc[j], 0, 0, 0);
    }
  }

#pragma unroll
  for (int r = 0; r < 4; ++r) {
    const float inv = 1.f / l_i[r];
    const int qq = q0 + w * 16 + ((lane >> 4) << 2) + r;
#pragma unroll
    for (int j = 0; j < 4; ++j)
      yattn[((size_t)b * LL + qq) * YSTR + 1024 + hh * EE + j * 16 + fm] =
          __float2bfloat16(oacc[j][r] * inv);
  }
}

// ---------------------------------------------------------------------------
// h = LN1(xf + combo); hn(bf16) = LN2(h).
// ---------------------------------------------------------------------------
__device__ __forceinline__ float block_sum512(float val, float* sm)
{
#pragma unroll
  for (int off = 32; off; off >>= 1) val += __shfl_xor(val, off, 64);
  const int wid = threadIdx.x >> 6;
  __syncthreads();
  if ((threadIdx.x & 63) == 0) sm[wid] = val;
  __syncthreads();
  return sm[0] + sm[1] + sm[2] + sm[3];
}

__global__ __launch_bounds__(256) void ln_fused(
    const float* __restrict__ xf, const float* __restrict__ combo,
    const float* __restrict__ g1, const float* __restrict__ b1,
    const float* __restrict__ g2, const float* __restrict__ b2,
    float* __restrict__ hout, __hip_bfloat16* __restrict__ hnout)
{
  __shared__ float sm[4];
  const size_t base = (size_t)blockIdx.x * DD;
  const int t = threadIdx.x;
  const float v0 = xf[base + t] + combo[base + t];
  const float v1 = xf[base + 256 + t] + combo[base + 256 + t];
  const float mean = block_sum512(v0 + v1, sm) * (1.f / DD);
  const float d0 = v0 - mean, d1 = v1 - mean;
  const float var = block_sum512(d0 * d0 + d1 * d1, sm) * (1.f / DD);
  const float rstd = rsqrtf(var + 1e-5f);
  const float h0 = d0 * rstd * g1[t] + b1[t];
  const float h1 = d1 * rstd * g1[t + 256] + b1[t + 256];
  hout[base + t] = h0;
  hout[base + 256 + t] = h1;
  const float mean2 = block_sum512(h0 + h1, sm) * (1.f / DD);
  const float e0 = h0 - mean2, e1 = h1 - mean2;
  const float var2 = block_sum512(e0 * e0 + e1 * e1, sm) * (1.f / DD);
  const float rstd2 = rsqrtf(var2 + 1e-6f);
  hnout[base + t] = __float2bfloat16(e0 * rstd2 * g2[t] + b2[t]);
  hnout[base + 256 + t] = __float2bfloat16(e1 * rstd2 * g2[t + 256] + b2[t + 256]);
}

// ---------------------------------------------------------------------------
extern "C" void kernel_launch(void* const* d_in, const int* in_sizes, int n_in,
                              void* d_out, int out_size, void* d_ws, size_t ws_size,
                              hipStream_t stream)
{
  const float* x         = (const float*)d_in[0];
  const float* Wq        = (const float*)d_in[2];
  const float* bq        = (const float*)d_in[3];
  const float* Wk        = (const float*)d_in[4];
  const float* bk        = (const float*)d_in[5];
  const float* Wv        = (const float*)d_in[6];
  const float* bv        = (const float*)d_in[7];
  const float* Wo        = (const float*)d_in[8];
  const float* bo        = (const float*)d_in[9];
  const float* in_proj_w = (const float*)d_in[10];
  const float* conv_w    = (const float*)d_in[11];
  const float* conv_b    = (const float*)d_in[12];
  const float* x_proj_w  = (const float*)d_in[13];
  const float* dt_proj_w = (const float*)d_in[14];
  const float* dt_proj_b = (const float*)d_in[15];
  const float* A_log     = (const float*)d_in[16];
  const float* D_ssm     = (const float*)d_in[17];
  const float* out_proj_w= (const float*)d_in[18];
  const float* ln1_g     = (const float*)d_in[19];
  const float* ln1_b     = (const float*)d_in[20];
  const float* ffn_w1    = (const float*)d_in[21];
  const float* ffn_b1    = (const float*)d_in[22];
  const float* ffn_w2    = (const float*)d_in[23];
  const float* ffn_b2    = (const float*)d_in[24];
  const float* ln2_g     = (const float*)d_in[25];
  const float* ln2_b     = (const float*)d_in[26];
  float* out = (float*)d_out;

  // ---- workspace layout (f32-unit offsets), peak 154.5 MB
  float* ws = (float*)d_ws;
  const size_t OF_XBF = 2506752;               // xbf bf16 | later hnbf
  const size_t OF_XZ  = OF_XBF + 2359296;      // xz bf16 [ML,2048]
  const size_t OF_UBF = OF_XZ + 9437184;       // ubf bf16 | later combo f32
  const size_t OF_XD  = OF_UBF + 4718592;      // xdbc bf16
  const size_t OF_DF  = OF_XD + 737280;        // deltab bf16 | ffbf (part 1)
  const size_t OF_QKV = OF_DF + 4718592;       // qkbuf+vtbf bf16 | ffbf (part 2)
  const size_t OF_YA  = OF_QKV + 7077888;      // yattn bf16 [ML,1536] | later hbuf f32
  const size_t OF_QB  = OF_YA + 7077888;       // qkv bias f32 [1536]

  __hip_bfloat16* wbf     = (__hip_bfloat16*)ws;
  __hip_bfloat16* xbf     = (__hip_bfloat16*)(ws + OF_XBF);
  __hip_bfloat16* hnbf    = (__hip_bfloat16*)(ws + OF_XBF);
  __hip_bfloat16* xz      = (__hip_bfloat16*)(ws + OF_XZ);
  __hip_bfloat16* ubf     = (__hip_bfloat16*)(ws + OF_UBF);
  float*          combo   = ws + OF_UBF;
  __hip_bfloat16* xdbc_bf = (__hip_bfloat16*)(ws + OF_XD);
  __hip_bfloat16* deltab  = (__hip_bfloat16*)(ws + OF_DF);
  __hip_bfloat16* ffbf    = (__hip_bfloat16*)(ws + OF_DF);
  __hip_bfloat16* qkbuf   = (__hip_bfloat16*)(ws + OF_QKV);
  __hip_bfloat16* vtbf    = (__hip_bfloat16*)(ws + OF_QKV + 4718592);
  __hip_bfloat16* yattn   = (__hip_bfloat16*)(ws + OF_YA);
  float*          hbuf    = ws + OF_YA;
  float*          qkvbias = ws + OF_QB;

  // weight offsets (bf16 elements) in wbf
  const size_t w_inproj = 0;          // 1048576
  const size_t w_xproj  = 1048576;    // rows padded 160->256 (262144)
  const size_t w_dt     = 1310720;    // 32768
  const size_t w_cat    = 1343488;    // [512, 1536] = out_proj | Wo (786432)
  const size_t w_q      = 2129920;    // q,k,v contiguous 1536x512 (786432)
  const size_t w_f1     = 2916352;    // 1048576
  const size_t w_f2     = 3964928;    // 1048576; total 5013504 bf16

  const dim3 thr(256);
#define CVT(src, dst, n) cvt_bf16<<<dim3(((n)/4 + 255)/256), thr, 0, stream>>>(src, dst, n)
#define GEMM(Abf, lda_, Woff, Bptr, Rptr, Cptr, C2ptr, N_, K_, act_, md_) \
  gemm_mfma<<<dim3((N_ + 127)/128, ML/128), thr, 0, stream>>>( \
      Abf, lda_, wbf + (Woff), Bptr, Rptr, (void*)(Cptr), (void*)(C2ptr), ML, N_, K_, act_, md_)

  hipMemsetAsync((void*)(wbf + w_xproj + (size_t)160 * 1024), 0, (size_t)96 * 1024 * 2, stream);
  CVT(in_proj_w, wbf + w_inproj, 1048576);
  CVT(x_proj_w,  wbf + w_xproj,  163840);
  CVT(dt_proj_w, wbf + w_dt,     32768);
  cvt_pack<<<dim3((524288 + 255)/256), thr, 0, stream>>>(
      out_proj_w, wbf + w_cat, 1024, 1536, 0,    524288);
  cvt_pack<<<dim3((262144 + 255)/256), thr, 0, stream>>>(
      Wo,         wbf + w_cat, 512,  1536, 1024, 262144);
  CVT(Wq,        wbf + w_q,           262144);
  CVT(Wk,        wbf + w_q + 262144,  262144);
  CVT(Wv,        wbf + w_q + 524288,  262144);
  CVT(ffn_w1,    wbf + w_f1,    1048576);
  CVT(ffn_w2,    wbf + w_f2,    1048576);
  CVT(x,         xbf,           ML * DD);
  hipMemcpyAsync(qkvbias,        bq, 512 * sizeof(float), hipMemcpyDeviceToDevice, stream);
  hipMemcpyAsync(qkvbias + 512,  bk, 512 * sizeof(float), hipMemcpyDeviceToDevice, stream);
  hipMemcpyAsync(qkvbias + 1024, bv, 512 * sizeof(float), hipMemcpyDeviceToDevice, stream);

  // ---- mamba preprocessing
  GEMM(xbf, DD, w_inproj, nullptr, nullptr, xz, nullptr, 2 * DI, DD, 0, 1);
  conv_silu<<<dim3((ML * DI) / 256), thr, 0, stream>>>(xz, conv_w, conv_b, ubf);
  GEMM(ubf, DI, w_xproj, nullptr, nullptr, xdbc_bf, nullptr, XS, DI, 0, 1);
  GEMM(xdbc_bf, XS, w_dt, dt_proj_b, nullptr, deltab, nullptr, DI, RR, 2, 1);

  // ---- attention (QKV fused GEMM, then flash attention)
  GEMM(xbf, DD, w_q, qkvbias, nullptr, qkbuf, vtbf, 3 * DD, DD, 0, 3);
  attn_mfma<<<dim3(LL / 64, BB * HH), thr, 0, stream>>>(qkbuf, vtbf, yattn);

  // ---- selective scan (4096 waves, 4/SIMD)
  scan_kernel<<<dim3(1024), thr, 0, stream>>>(
      deltab, ubf, xz, xdbc_bf, A_log, D_ssm, yattn);

  // ---- combined output projection: combo = y@out_proj^T + attn@Wo^T + bo
  GEMM(yattn, YSTR, w_cat, bo, nullptr, combo, nullptr, DD, YSTR, 0, 0);

  // ---- combine + LN1 + LN2
  ln_fused<<<dim3(ML), thr, 0, stream>>>(x, combo, ln1_g, ln1_b,
                                         ln2_g, ln2_b, hbuf, hnbf);

  // ---- FFN
  GEMM(hnbf, DD, w_f1, ffn_b1, nullptr, ffbf, nullptr, DFF, DD, 1, 1);
  GEMM(ffbf, DFF, w_f2, ffn_b2, hbuf, out, nullptr, DD, DFF, 0, 0);
#undef GEMM
#undef CVT
}